// Round 7
// baseline (189.511 us; speedup 1.0000x reference)
//
#include <hip/hip_runtime.h>
#include <hip/hip_bf16.h>
#include <math.h>

// Problem constants (B=8, C=128, H=W=64, G=2, gc=64, nH=4, dh=32, Hk=Wk=16, n=256)
#define HW 4096
#define NCH 128

typedef __attribute__((ext_vector_type(8))) short short8;
typedef __attribute__((ext_vector_type(4))) float f32x4;

__device__ __forceinline__ short f2bf(float f) {
  union { __hip_bfloat16 h; short s; } u;
  u.h = __float2bfloat16(f);
  return u.s;
}
__device__ __forceinline__ float bf2f(short s) {
  union { unsigned u; float f; } u;
  u.u = ((unsigned)(unsigned short)s) << 16;
  return u.f;
}
// unpack packed (hi<<16)|lo bf16 pair -> fp32 value hi+lo
__device__ __forceinline__ float upk(unsigned u) {
  union { unsigned u; float f; } a, b;
  a.u = u & 0xFFFF0000u;
  b.u = u << 16;
  return a.f + b.f;
}

// ---------------------------------------------------------------------------
// K1: fused transpose + q-conv (wq converted inline from fp32, L2-hot).
//  phase 1: stage x tile (128c x 64m) in LDS
//  phase 2: write xpk[b][m][c] = (bf16hi<<16)|bf16lo  (exact to ~2^-17)
//  phase 3: q MFMA bf16x3 split -> qT[b][m][o] fp32
// ---------------------------------------------------------------------------
__global__ __launch_bounds__(256) void xq_kernel(
    const float* __restrict__ x, const float* __restrict__ wq,
    unsigned* __restrict__ xpk, float* __restrict__ qT) {
  __shared__ float s[128][65];  // 33.3 KB
  int tid = threadIdx.x;
  int b = blockIdx.y;
  int m0 = blockIdx.x * 64;
  {
    int ml = tid & 63, ch = tid >> 6;
#pragma unroll
    for (int i = 0; i < 32; ++i) {
      int c = i * 4 + ch;
      s[c][ml] = x[((size_t)(b * NCH + c)) * HW + m0 + ml];
    }
  }
  __syncthreads();
  // phase 2: packed hi/lo write, coalesced along c
  {
    int c = tid & 127, mh = tid >> 7;
#pragma unroll
    for (int i = 0; i < 32; ++i) {
      int m = i * 2 + mh;
      float v = s[c][m];
      short hi = f2bf(v);
      unsigned lo = (unsigned short)f2bf(v - bf2f(hi));
      xpk[((size_t)(b * HW + m0 + m)) * NCH + c] =
          (((unsigned)(unsigned short)hi) << 16) | lo;
    }
  }
  // phase 3: q MFMA (weights converted inline)
  int w = tid >> 6, lane = tid & 63, l15 = lane & 15, qd = lane >> 4;
  int mrow = w * 16 + l15;
  f32x4 acc[8];
#pragma unroll
  for (int ot = 0; ot < 8; ++ot) acc[ot] = (f32x4){0.f, 0.f, 0.f, 0.f};
#pragma unroll
  for (int kc = 0; kc < 4; ++kc) {
    short8 ah, al;
#pragma unroll
    for (int j = 0; j < 8; ++j) {
      float v = s[kc * 32 + qd * 8 + j][mrow];
      short hi = f2bf(v);
      ah[j] = hi;
      al[j] = f2bf(v - bf2f(hi));
    }
#pragma unroll
    for (int ot = 0; ot < 8; ++ot) {
      const float* wr = wq + (size_t)(ot * 16 + l15) * NCH + kc * 32 + qd * 8;
      f32x4 w0 = *(const f32x4*)wr;
      f32x4 w1 = *(const f32x4*)(wr + 4);
      short8 bh, bl;
#pragma unroll
      for (int j = 0; j < 4; ++j) {
        short h0 = f2bf(w0[j]);
        bh[j] = h0;
        bl[j] = f2bf(w0[j] - bf2f(h0));
        short h1 = f2bf(w1[j]);
        bh[4 + j] = h1;
        bl[4 + j] = f2bf(w1[j] - bf2f(h1));
      }
      acc[ot] = __builtin_amdgcn_mfma_f32_16x16x32_bf16(ah, bh, acc[ot], 0, 0, 0);
      acc[ot] = __builtin_amdgcn_mfma_f32_16x16x32_bf16(al, bh, acc[ot], 0, 0, 0);
      acc[ot] = __builtin_amdgcn_mfma_f32_16x16x32_bf16(ah, bl, acc[ot], 0, 0, 0);
    }
  }
#pragma unroll
  for (int ot = 0; ot < 8; ++ot)
#pragma unroll
    for (int r = 0; r < 4; ++r)
      qT[((size_t)(b * HW + m0 + w * 16 + qd * 4 + r)) * NCH + ot * 16 + l15] =
          acc[ot][r];
}

// ---------------------------------------------------------------------------
// K2: fused conv_offset + grid_sample, plus prep side-blocks:
//  bid <  256 : main — wave computes pos/dm for 4 p (register-resident via
//               all-lane butterfly sums), then samples those p into xsT
//  bid <  320 : wk/wv/wo -> bf16
//  bid >= 320 : rpe -> padded f16 table rpe16[h][129][130] (zero border)
// ---------------------------------------------------------------------------
__device__ __forceinline__ float wsum64(float v) {
#pragma unroll
  for (int o = 32; o > 0; o >>= 1) v += __shfl_xor(v, o);
  return v;
}

__global__ __launch_bounds__(256) void offs_kernel(
    const float* __restrict__ qT, const float* __restrict__ w_dw,
    const float* __restrict__ ln_w, const float* __restrict__ w_off,
    const unsigned* __restrict__ xpk, const float* __restrict__ wk,
    const float* __restrict__ wv, const float* __restrict__ wo,
    const float* __restrict__ rpe, float* __restrict__ pos,
    short* __restrict__ xsT, short* __restrict__ wk_bf,
    short* __restrict__ wv_bf, short* __restrict__ wo_bf,
    _Float16* __restrict__ rpe16) {
  int tid = threadIdx.x;
  int bid = blockIdx.x;
  if (bid >= 256) {
    if (bid < 320) {
      int i = (bid - 256) * 256 + tid;
      wk_bf[i] = f2bf(wk[i]);
      wv_bf[i] = f2bf(wv[i]);
      wo_bf[i] = f2bf(wo[i]);
    } else {
      int i = (bid - 320) * 256 + tid;
      if (i < 4 * 16800) {
        int h = i / 16800, r = i % 16800;
        int y = r / 130, xx = r % 130;
        float v = 0.f;
        if (y >= 1 && y <= 127 && xx >= 1 && xx <= 127)
          v = rpe[(size_t)h * 16129 + (y - 1) * 127 + (xx - 1)];
        rpe16[i] = (_Float16)v;
      }
    }
    return;
  }
  int bg = bid >> 4;
  int p0 = (bid & 15) * 16;
  int c = tid & 63;  // lane
  int w = tid >> 6;
  int b = bg >> 1, ch0 = (bg & 1) * 64;
  const float* qp = qT + (size_t)b * HW * NCH + ch0 + c;
  const float* wd = w_dw + c * 25;
  float pyr[4], pxr[4], dmr[4];
#pragma unroll
  for (int i = 0; i < 4; ++i) {
    int p = p0 + w * 4 + i;
    int py = p >> 4, px = p & 15;
    float acc = 0.f;
#pragma unroll
    for (int ky = 0; ky < 5; ++ky) {
      int iy = 4 * py + ky - 2;
      if (iy < 0 || iy >= 64) continue;
#pragma unroll
      for (int kx = 0; kx < 5; ++kx) {
        int ix = 4 * px + kx - 2;
        if (ix < 0 || ix >= 64) continue;
        acc += wd[ky * 5 + kx] * qp[(size_t)(iy * 64 + ix) * NCH];
      }
    }
    float mean = wsum64(acc) * (1.f / 64.f);
    float msq = wsum64(acc * acc) * (1.f / 64.f);
    float var = msq - mean * mean;  // jnp.var (ddof=0)
    float g = acc * rsqrtf(var + 1e-5f) * ln_w[c];
    g = 0.5f * g * (1.f + erff(g * 0.70710678118654752f));  // exact GELU
    float o0 = wsum64(w_off[c] * g);
    float o1 = wsum64(w_off[64 + c] * g);
    float o2 = wsum64(w_off[128 + c] * g);
    // butterfly sums land in ALL lanes -> keep pos/dm in registers
    pyr[i] = tanhf(o0) * (1.f / 16.f) + ((py + 0.5f) * (1.f / 8.f) - 1.f);
    pxr[i] = tanhf(o1) * (1.f / 16.f) + ((px + 0.5f) * (1.f / 8.f) - 1.f);
    dmr[i] = 1.f / (1.f + expf(-o2));
    if (c == 0) {
      int idx = bg * 256 + p;
      pos[idx * 2] = pyr[i];
      pos[idx * 2 + 1] = pxr[i];
    }
  }
  // sample phase: same wave samples its own 4 p (no barrier needed)
  size_t rb = (size_t)b * HW * NCH + ch0 + c;
#pragma unroll
  for (int i = 0; i < 4; ++i) {
    int p = p0 + w * 4 + i;
    float gx = (pxr[i] + 1.f) * 31.5f;
    float gy = (pyr[i] + 1.f) * 31.5f;
    float x0f = floorf(gx), y0f = floorf(gy);
    int ix = (int)x0f, iy = (int)y0f;
    float fx = gx - x0f, fy = gy - y0f;
    float w00 = (1.f - fx) * (1.f - fy), w10 = fx * (1.f - fy);
    float w01 = (1.f - fx) * fy, w11 = fx * fy;
    bool vx0 = (ix >= 0 && ix < 64), vx1 = (ix + 1 >= 0 && ix + 1 < 64);
    bool vy0 = (iy >= 0 && iy < 64), vy1 = (iy + 1 >= 0 && iy + 1 < 64);
    if (!(vx0 && vy0)) w00 = 0.f;
    if (!(vx1 && vy0)) w10 = 0.f;
    if (!(vx0 && vy1)) w01 = 0.f;
    if (!(vx1 && vy1)) w11 = 0.f;
    int x0c = min(max(ix, 0), 63), x1c = min(max(ix + 1, 0), 63);
    int y0c = min(max(iy, 0), 63), y1c = min(max(iy + 1, 0), 63);
    float v = w00 * upk(xpk[rb + (size_t)(y0c * 64 + x0c) * NCH]) +
              w10 * upk(xpk[rb + (size_t)(y0c * 64 + x1c) * NCH]) +
              w01 * upk(xpk[rb + (size_t)(y1c * 64 + x0c) * NCH]) +
              w11 * upk(xpk[rb + (size_t)(y1c * 64 + x1c) * NCH]);
    xsT[((size_t)(b * 256 + p)) * NCH + ch0 + c] = f2bf(v * dmr[i]);
  }
}

// ---------------------------------------------------------------------------
// K3: k,v via MFMA from xsT.  kbf[bh][n][dh], vbf[bh][dh][n].
// grid (32 bh, 4 n-tiles of 64, 2 which) = 256 blocks (4 waves/CU).
// ---------------------------------------------------------------------------
__global__ __launch_bounds__(256) void kv_mfma_kernel(
    const short* __restrict__ xsT, const short* __restrict__ wk_bf,
    const short* __restrict__ wv_bf, short* __restrict__ kbf,
    short* __restrict__ vbf) {
  int tid = threadIdx.x;
  int w = tid >> 6, lane = tid & 63, l15 = lane & 15, qd = lane >> 4;
  int bh = blockIdx.x, b = bh >> 2;
  int n0 = blockIdx.y * 64 + w * 16;
  f32x4 acc[2];
  acc[0] = (f32x4){0.f, 0.f, 0.f, 0.f};
  acc[1] = (f32x4){0.f, 0.f, 0.f, 0.f};

  size_t xrow = ((size_t)(b * 256 + n0 + l15)) * NCH + qd * 8;
  if (blockIdx.z == 0) {  // K: A = xsT rows (n), B = wk rows (o)
#pragma unroll
    for (int kc = 0; kc < 4; ++kc) {
      short8 a = *(const short8*)&xsT[xrow + kc * 32];
#pragma unroll
      for (int ot = 0; ot < 2; ++ot) {
        short8 bb = *(const short8*)&wk_bf[(size_t)((bh & 3) * 32 + ot * 16 + l15) * NCH + kc * 32 + qd * 8];
        acc[ot] = __builtin_amdgcn_mfma_f32_16x16x32_bf16(a, bb, acc[ot], 0, 0, 0);
      }
    }
#pragma unroll
    for (int ot = 0; ot < 2; ++ot)
#pragma unroll
      for (int r = 0; r < 4; ++r)
        kbf[((size_t)(bh * 256 + n0 + qd * 4 + r)) * 32 + ot * 16 + l15] =
            f2bf(acc[ot][r]);
  } else {  // V: A = wv rows (o), B = xsT rows (n)
#pragma unroll
    for (int kc = 0; kc < 4; ++kc) {
      short8 bb = *(const short8*)&xsT[xrow + kc * 32];
#pragma unroll
      for (int ot = 0; ot < 2; ++ot) {
        short8 a = *(const short8*)&wv_bf[(size_t)((bh & 3) * 32 + ot * 16 + l15) * NCH + kc * 32 + qd * 8];
        acc[ot] = __builtin_amdgcn_mfma_f32_16x16x32_bf16(a, bb, acc[ot], 0, 0, 0);
      }
    }
#pragma unroll
    for (int ot = 0; ot < 2; ++ot)
#pragma unroll
      for (int r = 0; r < 4; ++r)
        vbf[((size_t)(bh * 32 + ot * 16 + qd * 4 + r)) * 256 + n0 + l15] =
            f2bf(acc[ot][r]);
  }
}

// ---------------------------------------------------------------------------
// K4: MFMA attention.  Padded-f16 RPE in LDS; P (raw exp, unnormalized)
// overlays the table after barrier 2; PV output scaled by inv in epilogue.
// ---------------------------------------------------------------------------
#define PROW 264       // bf16 elems per P row (528 B, 16B-aligned rows)
#define POS_OFF 33552  // byte offset of s_pos
#define LDS_BYTES 35600

__global__ __launch_bounds__(256) void attn_kernel(
    const float* __restrict__ qT, const short* __restrict__ kbf,
    const short* __restrict__ vbf, const float* __restrict__ pos,
    const _Float16* __restrict__ rpe16, short* __restrict__ outT) {
  __shared__ __align__(16) unsigned char s_raw[LDS_BYTES];
  _Float16* tab = (_Float16*)s_raw;
  float* s_pos = (float*)(s_raw + POS_OFF);
  short* s_p = (short*)s_raw;

  int tid = threadIdx.x;
  int wv = tid >> 6;
  int lane = tid & 63;
  int l15 = lane & 15;
  int qd = lane >> 4;
  int bh = blockIdx.y;
  int b = bh >> 2, h = bh & 3;
  int bg = b * 2 + (h >> 1);
  int m0 = blockIdx.x * 64 + wv * 16;

  {
    const uint4* src = (const uint4*)(rpe16 + (size_t)h * 16800);
    uint4* dst = (uint4*)s_raw;
    for (int i = tid; i < 2097; i += 256) dst[i] = src[i];
    const float* posg = pos + (size_t)bg * 512;
    s_pos[tid] = posg[tid];
    s_pos[256 + tid] = posg[256 + tid];
  }

  short8 qfrag;
  {
    const float* qg = qT + ((size_t)(b * HW + m0 + l15)) * NCH + h * 32 + qd * 8;
    f32x4 a0 = *(const f32x4*)qg;
    f32x4 a1 = *(const f32x4*)(qg + 4);
#pragma unroll
    for (int j = 0; j < 4; ++j) {
      qfrag[j] = f2bf(a0[j]);
      qfrag[4 + j] = f2bf(a1[j]);
    }
  }

  f32x4 acc[16];
  {
    const short* kb = kbf + ((size_t)bh * 256 + l15) * 32 + qd * 8;
#pragma unroll
    for (int t = 0; t < 16; ++t) {
      short8 kf = *(const short8*)(kb + t * 16 * 32);
      acc[t] = __builtin_amdgcn_mfma_f32_16x16x32_bf16(
          kf, qfrag, (f32x4){0.f, 0.f, 0.f, 0.f}, 0, 0, 0);
    }
  }
  __syncthreads();  // staging done

  int m = m0 + l15;
  float gy0 = ((((float)(m >> 6) + 0.5f) * (1.f / 32.f) - 1.f) * 0.5f + 1.f) * 63.f;
  float gx0 = ((((float)(m & 63) + 0.5f) * (1.f / 32.f) - 1.f) * 0.5f + 1.f) * 63.f;
  float mx = -1e30f;
#pragma unroll
  for (int t = 0; t < 16; ++t) {
    const f32x4* pp4 = (const f32x4*)&s_pos[(t * 16 + qd * 4) * 2];
    f32x4 pA = pp4[0];
    f32x4 pB = pp4[1];
    float py[4] = {pA[0], pA[2], pB[0], pB[2]};
    float px[4] = {pA[1], pA[3], pB[1], pB[3]};
#pragma unroll
    for (int r = 0; r < 4; ++r) {
      float gy = gy0 - py[r] * 31.5f;
      float gx = gx0 - px[r] * 31.5f;
      float y0f = floorf(gy), x0f = floorf(gx);
      float fy = gy - y0f, fx = gx - x0f;
      int base = (int)y0f * 130 + (int)x0f + 131;
      unsigned u0, u1;
      __builtin_memcpy(&u0, (const char*)tab + 2 * base, 4);
      __builtin_memcpy(&u1, (const char*)tab + 2 * base + 260, 4);
      union { unsigned u; _Float16 h[2]; } c0, c1;
      c0.u = u0;
      c1.u = u1;
      float t00 = (float)c0.h[0], t10 = (float)c0.h[1];
      float t01 = (float)c1.h[0], t11 = (float)c1.h[1];
      float r0 = t00 + fx * (t10 - t00);
      float r1 = t01 + fx * (t11 - t01);
      float bias = r0 + fy * (r1 - r0);
      float s = fmaf(acc[t][r], 0.17677669529663688f, bias);
      acc[t][r] = s;
      mx = fmaxf(mx, s);
    }
  }
  mx = fmaxf(mx, __shfl_xor(mx, 16));
  float M = fmaxf(mx, __shfl_xor(mx, 32));

  float sm = 0.f;
#pragma unroll
  for (int t = 0; t < 16; ++t) {
#pragma unroll
    for (int r = 0; r < 4; ++r) {
      float e = __expf(acc[t][r] - M);
      acc[t][r] = e;
      sm += e;
    }
  }
  sm += __shfl_xor(sm, 16);
  sm += __shfl_xor(sm, 32);
  float inv = 1.f / sm;

  __syncthreads();  // all table/pos reads done before P overlays

  // write raw exp P (bf16); normalization folded into the epilogue
  {
    short* pw = s_p + wv * 16 * PROW + l15 * PROW;
#pragma unroll
    for (int t = 0; t < 16; ++t) {
      int n = t * 16 + qd * 4;
      short4 pk;
      pk.x = f2bf(acc[t][0]);
      pk.y = f2bf(acc[t][1]);
      pk.z = f2bf(acc[t][2]);
      pk.w = f2bf(acc[t][3]);
      *(short4*)(pw + n) = pk;
    }
  }
  // no barrier: each wave reads only its own P region

  f32x4 o0 = {0.f, 0.f, 0.f, 0.f}, o1 = {0.f, 0.f, 0.f, 0.f};
  {
    const short* vb = vbf + ((size_t)bh * 32 + l15) * 256 + qd * 8;
    const short* pr = s_p + wv * 16 * PROW + l15 * PROW + qd * 8;
#pragma unroll
    for (int ch = 0; ch < 8; ++ch) {
      short8 pf = *(const short8*)(pr + ch * 32);
      short8 v0 = *(const short8*)(vb + ch * 32);
      short8 v1 = *(const short8*)(vb + 16 * 256 + ch * 32);
      o0 = __builtin_amdgcn_mfma_f32_16x16x32_bf16(v0, pf, o0, 0, 0, 0);
      o1 = __builtin_amdgcn_mfma_f32_16x16x32_bf16(v1, pf, o1, 0, 0, 0);
    }
  }
  {
    // PV D-column = m = l15 -> inv (per-m) applies uniformly to o0/o1
    size_t row = (size_t)(b * HW + m0 + l15) * NCH + h * 32 + qd * 4;
    short4 s0, s1;
    s0.x = f2bf(o0[0] * inv); s0.y = f2bf(o0[1] * inv);
    s0.z = f2bf(o0[2] * inv); s0.w = f2bf(o0[3] * inv);
    s1.x = f2bf(o1[0] * inv); s1.y = f2bf(o1[1] * inv);
    s1.z = f2bf(o1[2] * inv); s1.w = f2bf(o1[3] * inv);
    *(short4*)&outT[row] = s0;
    *(short4*)&outT[row + 16] = s1;
  }
}

// ---------------------------------------------------------------------------
// K5: final conv via MFMA: out[b][o][m] = sum_c wo[o][c] * outT[b][m][c]
// ---------------------------------------------------------------------------
__global__ __launch_bounds__(256) void wo_mfma_kernel(
    const short* __restrict__ attnT, const short* __restrict__ wo_bf,
    float* __restrict__ out) {
  int tid = threadIdx.x;
  int wv = tid >> 6;
  int lane = tid & 63;
  int l15 = lane & 15;
  int qd = lane >> 4;
  int b = blockIdx.x >> 6;
  int m0 = (blockIdx.x & 63) * 64 + wv * 16;

  f32x4 acc[8];
#pragma unroll
  for (int ot = 0; ot < 8; ++ot) acc[ot] = (f32x4){0.f, 0.f, 0.f, 0.f};

  const short* arow = attnT + (size_t)(b * HW + m0 + l15) * NCH + qd * 8;
  const short* wrow = wo_bf + (size_t)l15 * NCH + qd * 8;
#pragma unroll
  for (int kc = 0; kc < 4; ++kc) {
    short8 afrag = *(const short8*)(arow + kc * 32);
#pragma unroll
    for (int ot = 0; ot < 8; ++ot) {
      short8 bfrag = *(const short8*)(wrow + (size_t)ot * 16 * NCH + kc * 32);
      acc[ot] = __builtin_amdgcn_mfma_f32_16x16x32_bf16(afrag, bfrag, acc[ot],
                                                        0, 0, 0);
    }
  }
#pragma unroll
  for (int ot = 0; ot < 8; ++ot) {
    float* op = out + ((size_t)b * NCH + ot * 16 + l15) * HW + m0 + qd * 4;
    *(f32x4*)op = acc[ot];
  }
}

// ---------------------------------------------------------------------------
// launch  (5 kernels: xq, offs(+prep), kv, attn, wo)
// ---------------------------------------------------------------------------
extern "C" void kernel_launch(void* const* d_in, const int* in_sizes, int n_in,
                              void* d_out, int out_size, void* d_ws,
                              size_t ws_size, hipStream_t stream) {
  const float* x = (const float*)d_in[0];
  const float* w_dw = (const float*)d_in[1];
  const float* ln_w = (const float*)d_in[2];
  const float* w_off = (const float*)d_in[3];
  const float* wq = (const float*)d_in[4];
  const float* wk = (const float*)d_in[5];
  const float* wv = (const float*)d_in[6];
  const float* wo = (const float*)d_in[7];
  const float* rpe = (const float*)d_in[8];
  float* out = (float*)d_out;

  // qT lives in d_out (dead before wo_mfma writes out).
  // outT aliases xpk's start (xpk dead after offs_kernel's sampling).
  float* qT = out;
  short* sb = (short*)d_ws;
  unsigned* xpk = (unsigned*)sb;        // 4194304 uints (16.7 MB)
  short* outT = sb;                     // 4194304 bf16 (8.4 MB), alias
  short* xsT = sb + 8388608;            // 262144
  short* kbf = sb + 8650752;            // 262144
  short* vbf = sb + 8912896;            // 262144
  short* wk_bf = sb + 9175040;          // 16384
  short* wv_bf = sb + 9191424;          // 16384
  short* wo_bf = sb + 9207808;          // 16384
  _Float16* rpe16 = (_Float16*)(sb + 9224192);  // 67200 f16 (16B-aligned)
  float* pos = (float*)(sb + 9291392);  // 8192 fp32 (16B-aligned)
  // total ~18.6 MB

  xq_kernel<<<dim3(64, 8), 256, 0, stream>>>(x, wq, xpk, qT);
  offs_kernel<<<583, 256, 0, stream>>>(qT, w_dw, ln_w, w_off, xpk, wk, wv, wo,
                                       rpe, pos, xsT, wk_bf, wv_bf, wo_bf,
                                       rpe16);
  kv_mfma_kernel<<<dim3(32, 4, 2), 256, 0, stream>>>(xsT, wk_bf, wv_bf, kbf,
                                                     vbf);
  attn_kernel<<<dim3(64, 32), 256, 0, stream>>>(qT, kbf, vbf, pos, rpe16,
                                                outT);
  wo_mfma_kernel<<<512, 256, 0, stream>>>(outT, wo_bf, out);
}